// Round 9
// baseline (168.495 us; speedup 1.0000x reference)
//
#include <hip/hip_runtime.h>

#define NQ 22
#define DIMN (1u << NQ)

// ---------------- compile-time circuit algebra (circuit is fixed) ----------------
struct MaskSet {
    unsigned L[NQ];      // CNOT-ring layer over GF(2): bit b of Lx = parity(x & L[b])
    unsigned Linv[NQ];
    unsigned xm[NQ];     // conjugated X masks
    unsigned zm[NQ];     // conjugated Z masks (suffix masks)
    unsigned frowHi[5];  // P-toggle masks for y bits 17..21 (columns of Linv)
};

constexpr MaskSet buildMasks() {
    MaskSet M{};
    for (int b = 0; b < NQ; ++b) M.L[b] = 1u << b;
    for (int q = 0; q < NQ; ++q) {
        int bc = NQ - 1 - q, bt = NQ - 1 - ((q + 1) % NQ);
        M.L[bt] ^= M.L[bc];
    }
    unsigned mat[NQ] = {}, aug[NQ] = {};
    for (int b = 0; b < NQ; ++b) { mat[b] = M.L[b]; aug[b] = 1u << b; }
    for (int col = 0; col < NQ; ++col) {
        int piv = col;
        while (!((mat[piv] >> col) & 1u)) ++piv;
        unsigned tm = mat[piv]; mat[piv] = mat[col]; mat[col] = tm;
        unsigned ta = aug[piv]; aug[piv] = aug[col]; aug[col] = ta;
        for (int r = 0; r < NQ; ++r)
            if (r != col && ((mat[r] >> col) & 1u)) { mat[r] ^= mat[col]; aug[r] ^= aug[col]; }
    }
    for (int b = 0; b < NQ; ++b) M.Linv[b] = aug[b];
    for (int j = 0; j < NQ; ++j) {
        int b = NQ - 1 - j;
        unsigned xmv = 0;
        for (int r = 0; r < NQ; ++r)
            if ((aug[r] >> b) & 1u) xmv |= 1u << r;
        M.xm[j] = xmv;       // q0..9: {21-j,20-j}; q10..20: low pairs; q21: {0,20,21}
        M.zm[j] = M.L[b];    // suffix masks
    }
    for (int j = 0; j < 5; ++j) {
        unsigned f = 0;
        for (int r = 0; r < NQ; ++r)
            if ((aug[r] >> (17 + j)) & 1u) f |= 1u << r;
        M.frowHi[j] = f;
    }
    return M;
}
constexpr int topbit_c(unsigned v) { int b = 0; while (v >> (b + 1)) ++b; return b; }
constexpr unsigned unionHi() {
    MaskSet M = buildMasks();
    unsigned u = 0;
    for (int j = 0; j < 5; ++j) u |= M.frowHi[j];
    return u;
}
static_assert((unionHi() & 0xFFFFu) == 0, "frowHi must only touch bits 16..21");

__device__ __forceinline__ float wave_sum(float v) {
    v += __shfl_down(v, 32); v += __shfl_down(v, 16); v += __shfl_down(v, 8);
    v += __shfl_down(v, 4);  v += __shfl_down(v, 2);  v += __shfl_down(v, 1);
    return v;
}
__device__ __forceinline__ float fflip(float v, unsigned sbit31) {
    return __int_as_float(__float_as_int(v) ^ (int)sbit31);
}
// scalar-address LDS swizzle (bits 3..5 ^= bits 6..8); float4-group form
__device__ __forceinline__ unsigned psw(unsigned i)  { return i ^ (((i >> 6) & 7u) << 3); }
__device__ __forceinline__ unsigned pg4(unsigned g)  { return g ^ (((g >> 4) & 7u) << 1); }

// ---------------- prep: zero accumulators, compute cos/sin tables ----------------
__global__ __launch_bounds__(256) void k_prep(const float* __restrict__ theta,
                                              float* __restrict__ acc,
                                              float* __restrict__ trig) {
    int t = threadIdx.x;
    acc[t] = 0.f;
    if (t < 2 * NQ) {
        int l = t / NQ, q = t % NQ, b = NQ - 1 - q;
        float h = 0.5f * theta[t];
        trig[l * 2 * NQ + b]      = cosf(h);
        trig[l * 2 * NQ + NQ + b] = sinf(h);
    }
}

// ---- generator in e=bits17..21 tile + gates 17..21 + measure q1,q2,q3 ----
__global__ __launch_bounds__(256, 1) void k_genHi(float* __restrict__ phi,
                                                  const float* __restrict__ trig,
                                                  float* __restrict__ acc) {
    constexpr MaskSet M = buildMasks();
    __shared__ float red[4 * 12];
    unsigned base = blockIdx.x * 256u + threadIdx.x;       // y bits 0..16
    unsigned P0 = 0;
#pragma unroll
    for (int b = 0; b < NQ; ++b)
        P0 |= ((unsigned)__popc(base & M.Linv[b]) & 1u) << b;
    float pc = 1.f;
#pragma unroll
    for (int b = 1; b < 16; ++b) {
        float cvb = trig[b], svb = trig[NQ + b];
        pc *= ((P0 >> b) & 1u) ? svb : cvb;
    }
    float cv0 = trig[0], sv0 = trig[NQ];
    float C0 = pc * ((P0 & 1u) ? sv0 : cv0);
    float C1 = pc * ((P0 & 1u) ? cv0 : -sv0);
    float cb[6], sb[6];
#pragma unroll
    for (int k = 0; k < 6; ++k) { cb[k] = trig[16 + k]; sb[k] = trig[NQ + 16 + k]; }
    unsigned u0 = P0 >> 16;                                // 6 bits
    float v0[32], v1[32];
#pragma unroll
    for (int e = 0; e < 32; ++e) {
        unsigned F = 0;
        if (e & 1)  F ^= M.frowHi[0];
        if (e & 2)  F ^= M.frowHi[1];
        if (e & 4)  F ^= M.frowHi[2];
        if (e & 8)  F ^= M.frowHi[3];
        if (e & 16) F ^= M.frowHi[4];
        unsigned u = u0 ^ (F >> 16);
        float vp = (u & 1u) ? sb[0] : cb[0];
#pragma unroll
        for (int k = 1; k < 6; ++k) vp *= ((u >> k) & 1u) ? sb[k] : cb[k];
        v0[e] = vp * C0;
        v1[e] = vp * C1;
    }
    float c2[5], s2[5];
#pragma unroll
    for (int j = 0; j < 5; ++j) {
        c2[j] = trig[2 * NQ + 17 + j];
        s2[j] = trig[3 * NQ + 17 + j];
    }
#pragma unroll
    for (int j = 0; j < 5; ++j) {
#pragma unroll
        for (int e = 0; e < 32; ++e) {
            if (!(e & (1 << j))) {
                int e1 = e | (1 << j);
                float a0 = v0[e], a1 = v0[e1];
                v0[e]  = c2[j] * a0 - s2[j] * a1;
                v0[e1] = s2[j] * a0 + c2[j] * a1;
                float b0 = v1[e], b1 = v1[e1];
                v1[e]  = c2[j] * b0 - s2[j] * b1;
                v1[e1] = s2[j] * b0 + c2[j] * b1;
            }
        }
    }
#pragma unroll
    for (int e = 0; e < 32; ++e) {
        unsigned a = base | ((unsigned)e << 17);
        phi[a] = v0[e];
        phi[DIMN + a] = v1[e];
    }
    int lane = threadIdx.x & 63, w = threadIdx.x >> 6;
#pragma unroll
    for (int i = 1; i <= 3; ++i) {
        unsigned ex  = M.xm[i] >> 17;
        unsigned zme = M.zm[i] >> 17;
        float t00 = 0.f, t11 = 0.f, t01 = 0.f, u01 = 0.f;
#pragma unroll
        for (int e = 0; e < 32; ++e) {
            int ep = e ^ (int)ex;
            t00 += v0[e] * v0[ep];
            t11 += v1[e] * v1[ep];
            float p = v0[e] * v1[ep];
            t01 += p;
            unsigned sg = ((unsigned)__popc((unsigned)ep & zme) & 1u) << 31;
            u01 += fflip(p, sg);
        }
        float vals[4] = { t00, t11, t01, u01 };
#pragma unroll
        for (int j = 0; j < 4; ++j) {
            float v = wave_sum(vals[j]);
            if (lane == 0) red[w * 12 + (i - 1) * 4 + j] = v;
        }
    }
    __syncthreads();
    int t = threadIdx.x;
    if (t < 12) {
        float r = red[t] + red[12 + t] + red[24 + t] + red[36 + t];
        atomicAdd(&acc[4 + t], r);                          // acc[4..15] = q1..q3
    }
}

// ---- e=bits12..16 tile: gates 12..16 + measure q5..q8 ----
__global__ __launch_bounds__(256, 1) void k_midA(float* __restrict__ phi,
                                                 const float* __restrict__ trig,
                                                 float* __restrict__ acc) {
    constexpr MaskSet M = buildMasks();
    __shared__ float red[4 * 16];
    unsigned tid = blockIdx.x * 256u + threadIdx.x;        // [0, 2^17)
    unsigned base = (tid & 0xFFFu) | ((tid >> 12) << 17);  // bits 0..11 + 17..21
    float v0[32], v1[32];
#pragma unroll
    for (int e = 0; e < 32; ++e) {
        unsigned a = base | ((unsigned)e << 12);
        v0[e] = phi[a];
        v1[e] = phi[DIMN + a];
    }
    float c[5], s[5];
#pragma unroll
    for (int j = 0; j < 5; ++j) {
        c[j] = trig[2 * NQ + 12 + j];
        s[j] = trig[3 * NQ + 12 + j];
    }
#pragma unroll
    for (int j = 0; j < 5; ++j) {
#pragma unroll
        for (int e = 0; e < 32; ++e) {
            if (!(e & (1 << j))) {
                int e1 = e | (1 << j);
                float a0 = v0[e], a1 = v0[e1];
                v0[e]  = c[j] * a0 - s[j] * a1;
                v0[e1] = s[j] * a0 + c[j] * a1;
                float b0 = v1[e], b1 = v1[e1];
                v1[e]  = c[j] * b0 - s[j] * b1;
                v1[e1] = s[j] * b0 + c[j] * b1;
            }
        }
    }
#pragma unroll
    for (int e = 0; e < 32; ++e) {
        unsigned a = base | ((unsigned)e << 12);
        phi[a] = v0[e];
        phi[DIMN + a] = v1[e];
    }
    int lane = threadIdx.x & 63, w = threadIdx.x >> 6;
#pragma unroll
    for (int i = 5; i <= 8; ++i) {
        unsigned ex  = (M.xm[i] >> 12) & 31u;
        unsigned zme = (M.zm[i] >> 12) & 31u;
        unsigned bs31 = ((unsigned)__popc(base & M.zm[i]) & 1u) << 31;
        float t00 = 0.f, t11 = 0.f, t01 = 0.f, u01 = 0.f;
#pragma unroll
        for (int e = 0; e < 32; ++e) {
            int ep = e ^ (int)ex;
            t00 += v0[e] * v0[ep];
            t11 += v1[e] * v1[ep];
            float p = v0[e] * v1[ep];
            t01 += p;
            unsigned sg = ((unsigned)__popc((unsigned)ep & zme) & 1u) << 31;
            u01 += fflip(p, sg ^ bs31);
        }
        float vals[4] = { t00, t11, t01, u01 };
#pragma unroll
        for (int j = 0; j < 4; ++j) {
            float v = wave_sum(vals[j]);
            if (lane == 0) red[w * 16 + (i - 5) * 4 + j] = v;
        }
    }
    __syncthreads();
    int t = threadIdx.x;
    if (t < 16) {
        float r = red[t] + red[16 + t] + red[32 + t] + red[48 + t];
        atomicAdd(&acc[20 + t], r);                         // acc[20..35] = q5..q8
    }
}

// ---- RY layer 2 bits 0..11 (512 thr, 4 register stages) + q10..q20 X/Y + ALL Z ----
__global__ __launch_bounds__(512, 4) void k_low(float* __restrict__ phi,
                                                const float* __restrict__ trig,
                                                float* __restrict__ acc) {
    constexpr MaskSet M = buildMasks();
    __shared__ float As[4096];
    __shared__ float Bs[4096];
    __shared__ float red[384];
    float4* As4 = (float4*)As;
    float4* Bs4 = (float4*)Bs;
    int t = threadIdx.x;                                  // 0..511
    int lane = t & 63, w = t >> 6;                        // 8 waves
    unsigned base = blockIdx.x * 4096u;
    float a[8], b[8];
    unsigned sz1 = (((unsigned)t >> 3) & 7u) << 3;        // phase-1 xor (const/thread)
    unsigned sz3 = (((unsigned)t >> 6) & 7u) << 3;        // phase-3 xor (const/thread)

    // ---- phase 0: load i = 8t+k, gates bits 0..2 ----
    {
        const float4* g0 = (const float4*)(phi + base);
        const float4* g1 = (const float4*)(phi + DIMN + base);
#pragma unroll
        for (int h = 0; h < 2; ++h) {
            float4 va = g0[2 * t + h];
            a[4 * h] = va.x; a[4 * h + 1] = va.y; a[4 * h + 2] = va.z; a[4 * h + 3] = va.w;
            float4 vb = g1[2 * t + h];
            b[4 * h] = vb.x; b[4 * h + 1] = vb.y; b[4 * h + 2] = vb.z; b[4 * h + 3] = vb.w;
        }
#pragma unroll
        for (int g = 0; g < 3; ++g) {
            float c = trig[2 * NQ + g], s = trig[3 * NQ + g];
#pragma unroll
            for (int e = 0; e < 8; ++e) {
                if (!(e & (1 << g))) {
                    int e1 = e | (1 << g);
                    float x0 = a[e], x1 = a[e1];
                    a[e] = c * x0 - s * x1; a[e1] = s * x0 + c * x1;
                    float y0 = b[e], y1 = b[e1];
                    b[e] = c * y0 - s * y1; b[e1] = s * y0 + c * y1;
                }
            }
        }
#pragma unroll
        for (int h = 0; h < 2; ++h) {
            unsigned f4 = (2u * t + h) ^ (sz1 >> 2);
            As4[f4] = make_float4(a[4 * h], a[4 * h + 1], a[4 * h + 2], a[4 * h + 3]);
            Bs4[f4] = make_float4(b[4 * h], b[4 * h + 1], b[4 * h + 2], b[4 * h + 3]);
        }
    }
    __syncthreads();

    // ---- phase 1: own bits 3..5 ----
    {
#pragma unroll
        for (int k = 0; k < 8; ++k) {
            unsigned i = ((unsigned)t & 7u) | ((unsigned)k << 3) | (((unsigned)t >> 3) << 6);
            a[k] = As[i ^ sz1];
            b[k] = Bs[i ^ sz1];
        }
#pragma unroll
        for (int g = 0; g < 3; ++g) {
            float c = trig[2 * NQ + 3 + g], s = trig[3 * NQ + 3 + g];
#pragma unroll
            for (int e = 0; e < 8; ++e) {
                if (!(e & (1 << g))) {
                    int e1 = e | (1 << g);
                    float x0 = a[e], x1 = a[e1];
                    a[e] = c * x0 - s * x1; a[e1] = s * x0 + c * x1;
                    float y0 = b[e], y1 = b[e1];
                    b[e] = c * y0 - s * y1; b[e1] = s * y0 + c * y1;
                }
            }
        }
#pragma unroll
        for (int k = 0; k < 8; ++k) {
            unsigned i = ((unsigned)t & 7u) | ((unsigned)k << 3) | (((unsigned)t >> 3) << 6);
            As[i ^ sz1] = a[k];
            Bs[i ^ sz1] = b[k];
        }
    }
    __syncthreads();

    // ---- phase 2: own bits 6..8 ----
    {
#pragma unroll
        for (int k = 0; k < 8; ++k) {
            unsigned i = ((unsigned)t & 63u) | ((unsigned)k << 6) | (((unsigned)t >> 6) << 9);
            unsigned p = i ^ ((unsigned)k << 3);
            a[k] = As[p];
            b[k] = Bs[p];
        }
#pragma unroll
        for (int g = 0; g < 3; ++g) {
            float c = trig[2 * NQ + 6 + g], s = trig[3 * NQ + 6 + g];
#pragma unroll
            for (int e = 0; e < 8; ++e) {
                if (!(e & (1 << g))) {
                    int e1 = e | (1 << g);
                    float x0 = a[e], x1 = a[e1];
                    a[e] = c * x0 - s * x1; a[e1] = s * x0 + c * x1;
                    float y0 = b[e], y1 = b[e1];
                    b[e] = c * y0 - s * y1; b[e1] = s * y0 + c * y1;
                }
            }
        }
#pragma unroll
        for (int k = 0; k < 8; ++k) {
            unsigned i = ((unsigned)t & 63u) | ((unsigned)k << 6) | (((unsigned)t >> 6) << 9);
            unsigned p = i ^ ((unsigned)k << 3);
            As[p] = a[k];
            Bs[p] = b[k];
        }
    }
    __syncthreads();

    // ---- phase 3: own bits 9..11, gates 9..11, write out (global + LDS) ----
    {
#pragma unroll
        for (int k = 0; k < 8; ++k) {
            unsigned i = (unsigned)t | ((unsigned)k << 9);
            a[k] = As[i ^ sz3];
            b[k] = Bs[i ^ sz3];
        }
#pragma unroll
        for (int g = 0; g < 3; ++g) {
            float c = trig[2 * NQ + 9 + g], s = trig[3 * NQ + 9 + g];
#pragma unroll
            for (int e = 0; e < 8; ++e) {
                if (!(e & (1 << g))) {
                    int e1 = e | (1 << g);
                    float x0 = a[e], x1 = a[e1];
                    a[e] = c * x0 - s * x1; a[e1] = s * x0 + c * x1;
                    float y0 = b[e], y1 = b[e1];
                    b[e] = c * y0 - s * y1; b[e1] = s * y0 + c * y1;
                }
            }
        }
#pragma unroll
        for (int k = 0; k < 8; ++k) {
            unsigned i = (unsigned)t | ((unsigned)k << 9);
            phi[base + i] = a[k];
            phi[DIMN + base + i] = b[k];
            As[i ^ sz3] = a[k];
            Bs[i ^ sz3] = b[k];
        }
    }

    // ---- Z measurement: per-channel j-tree (j = bits 9..11) + Walsh lane chain ----
    // slots per (wave, channel): 0=SS, 1=T9, 2=T10, 3=T11, 4+m = f(m), m=0..5
#pragma unroll
    for (int c = 0; c < 3; ++c) {
        float p[8];
#pragma unroll
        for (int j = 0; j < 8; ++j)
            p[j] = (c == 0) ? a[j] * a[j] : (c == 1) ? b[j] * b[j] : a[j] * b[j];
        float a1[4], b1[4];
#pragma unroll
        for (int j = 0; j < 4; ++j) { a1[j] = p[j] + p[j + 4]; b1[j] = p[j] - p[j + 4]; }
        float a2[2], b2[2];
#pragma unroll
        for (int j = 0; j < 2; ++j) { a2[j] = a1[j] + a1[j + 2]; b2[j] = b1[j] - b1[j + 2]; }
        float SS  = a2[0] + a2[1];
        float T11 = (b1[0] + b1[1]) + (b1[2] + b1[3]);   // sign parity(i>>11)
        float T10 = b2[0] + b2[1];                        // sign parity(i>>10)
        float T9  = b2[0] - b2[1];                        // sign parity(i>>9)
        float v;
        v = wave_sum(SS);  if (lane == 0) red[w * 30 + c * 10 + 0] = v;
        v = wave_sum(T9);  if (lane == 0) red[w * 30 + c * 10 + 1] = v;
        v = wave_sum(T10); if (lane == 0) red[w * 30 + c * 10 + 2] = v;
        v = wave_sum(T11); if (lane == 0) red[w * 30 + c * 10 + 3] = v;
        float u = T9;
#pragma unroll
        for (int bl = 5; bl >= 0; --bl) {
            u = u - __shfl_xor(u, 1 << bl);
            float f = u;
#pragma unroll
            for (int bb = bl - 1; bb >= 0; --bb) f += __shfl_xor(f, 1 << bb);
            if (lane == 0) red[w * 30 + c * 10 + 4 + bl] = f;
        }
    }
    __syncthreads();
    if (t < 66) {
        int c = t % 3, q = t / 3;
        unsigned bs = (unsigned)__popc(base & M.zm[q]) & 1u;
        float val = 0.f;
        if (q >= 1 && q <= 9) {
#pragma unroll
            for (int w2 = 0; w2 < 8; ++w2) val += red[w2 * 30 + c * 10 + 0];
        } else if (q >= 10 && q <= 12) {
            int slot = (q == 10) ? 3 : (q == 11) ? 2 : 1;
#pragma unroll
            for (int w2 = 0; w2 < 8; ++w2) val += red[w2 * 30 + c * 10 + slot];
        } else if (q >= 13 && q <= 15) {
#pragma unroll
            for (int w2 = 0; w2 < 8; ++w2) {
                unsigned sg = (q == 13) ? ((unsigned)(w2 >> 2) & 1u)
                            : (q == 14) ? ((((unsigned)w2 >> 1) ^ ((unsigned)w2 >> 2)) & 1u)
                                        : ((unsigned)__popc((unsigned)w2) & 1u);
                float r = red[w2 * 30 + c * 10 + 1];
                val += sg ? -r : r;
            }
        } else {                                          // q=16..21 -> m=5..0; q=0 -> m=0
            int m = (q == 0) ? 0 : 21 - q;
#pragma unroll
            for (int w2 = 0; w2 < 8; ++w2) {
                unsigned sg = (unsigned)__popc((unsigned)w2) & 1u;
                float r = red[w2 * 30 + c * 10 + 4 + m];
                val += sg ? -r : r;
            }
        }
        atomicAdd(&acc[4 * NQ + 3 * q + c], bs ? -val : val);
    }
    __syncthreads();

    // ---- X/Y: q10,q11 in-register (k = bits 9..11) ----
#pragma unroll
    for (int qi = 10; qi <= 11; ++qi) {
        unsigned exk = (M.xm[qi] >> 9) & 7u;
        unsigned zmk = (M.zm[qi] >> 9) & 7u;
        unsigned zb31 = ((unsigned)__popc(base & M.zm[qi]) & 1u) << 31;
        float t00 = 0.f, t11 = 0.f, t01 = 0.f, u01 = 0.f;
#pragma unroll
        for (int k = 0; k < 8; ++k) {
            int kp = k ^ (int)exk;
            t00 += a[k] * a[kp];
            t11 += b[k] * b[kp];
            float p = a[k] * b[kp];
            t01 += p;
            unsigned sg = ((unsigned)__popc((unsigned)kp & zmk) & 1u) << 31;
            u01 += fflip(p, sg ^ zb31);
        }
        float vals[4] = { t00, t11, t01, u01 };
#pragma unroll
        for (int j = 0; j < 4; ++j) {
            float v = wave_sum(vals[j]);
            if (lane == 0) red[w * 44 + (qi - 10) * 4 + j] = v;
        }
    }

    // ---- X/Y: q12..q19 via LDS pair iteration (single pass, 512 pair-groups) ----
#pragma unroll
    for (int i = 2; i < 10; ++i) {
        unsigned m = M.xm[10 + i], zm = M.zm[10 + i];
        unsigned zb = (unsigned)__popc(base & zm) & 1u;
        int gb = topbit_c(M.xm[10 + i]) - 2;
        unsigned mg4 = m >> 2;
        unsigned swap2 = m & 3u;                          // 0 or 2
        float t00 = 0.f, t11 = 0.f, t01 = 0.f, u01 = 0.f;
        {
            unsigned gc = (unsigned)t;                    // [0,512) pair-groups
            unsigned g = ((gc >> gb) << (gb + 1)) | (gc & ((1u << gb) - 1u));
            unsigned gx = g ^ mg4;
            float4 a0 = As4[pg4(g)],  a1 = Bs4[pg4(g)];
            float4 b0 = As4[pg4(gx)], b1 = Bs4[pg4(gx)];
            if (swap2) {
                b0 = make_float4(b0.z, b0.w, b0.x, b0.y);
                b1 = make_float4(b1.z, b1.w, b1.x, b1.y);
            }
            unsigned szg = ((unsigned)__popc((g << 2) & zm) + zb) & 1u;
            unsigned szx = ((unsigned)__popc((gx << 2) & zm) + zb) & 1u;
            unsigned fg = szg << 31, fx = szx << 31;
            const float* A0 = &a0.x; const float* A1 = &a1.x;
            const float* B0 = &b0.x; const float* B1 = &b1.x;
#pragma unroll
            for (int j = 0; j < 4; ++j) {
                t00 += A0[j] * B0[j];
                t11 += A1[j] * B1[j];
                float p = A0[j] * B1[j], r2 = B0[j] * A1[j];
                t01 += p + r2;
                u01 += fflip(p, fx) + fflip(r2, fg);
            }
        }
        t00 *= 2.f; t11 *= 2.f;
        float vals[4] = { t00, t11, t01, u01 };
#pragma unroll
        for (int j = 0; j < 4; ++j) {
            float v = wave_sum(vals[j]);
            if (lane == 0) red[w * 44 + 4 * i + j] = v;
        }
    }

    // ---- X/Y: q20 (m=3, partner within float4) ----
    {
        unsigned zm = M.zm[20];
        unsigned zb = (unsigned)__popc(base & zm) & 1u;
        float t00 = 0.f, t11 = 0.f, t01 = 0.f, u01 = 0.f;
#pragma unroll
        for (int k2 = 0; k2 < 2; ++k2) {
            unsigned g = (unsigned)t + 512u * k2;
            float4 a0 = As4[pg4(g)], a1 = Bs4[pg4(g)];
            unsigned szg = ((unsigned)__popc((g << 2) & zm) + zb) & 1u;
            const float* A0 = &a0.x; const float* A1 = &a1.x;
#pragma unroll
            for (int j = 0; j < 4; ++j) {
                int jx = j ^ 3;
                float p = A0[j] * A0[jx];
                float q2 = A1[j] * A1[jx];
                float cr = A0[j] * A1[jx];
                t00 += p; t11 += q2; t01 += cr;
                unsigned sj = ((unsigned)(jx >> 1) & 1u) ^ szg;   // zm&3 == 2
                u01 += fflip(cr, sj << 31);
            }
        }
        float vals[4] = { t00, t11, t01, u01 };
#pragma unroll
        for (int j = 0; j < 4; ++j) {
            float v = wave_sum(vals[j]);
            if (lane == 0) red[w * 44 + 40 + j] = v;
        }
    }
    __syncthreads();
    if (t < 44) {
        float r = 0.f;
#pragma unroll
        for (int w2 = 0; w2 < 8; ++w2) r += red[w2 * 44 + t];
        atomicAdd(&acc[40 + t], r);
    }
}

// ------- slice X/Y measurements for q0, q4, q9, q21 — grid (256, 4) -----------
struct Meas4Arg { unsigned xm[4]; unsigned zm[4]; int gbit[4]; int qn[4]; };

__global__ __launch_bounds__(256) void k_measS(const float* __restrict__ phi,
                                               float* __restrict__ acc,
                                               Meas4Arg M) {
    __shared__ float red[16];
    int t = threadIdx.x;
    int slice = blockIdx.y;
    unsigned m = M.xm[slice], zm = M.zm[slice];
    int gb = M.gbit[slice];
    unsigned mg4 = m >> 2;
    unsigned ml2 = m & 3u;                      // 0 or 1
    unsigned zl = zm & 3u;
    unsigned pg31[4], px31[4];
#pragma unroll
    for (int j = 0; j < 4; ++j) {
        pg31[j] = (((unsigned)__popc((unsigned)j & zl) & 1u) << 31);
        px31[j] = (((unsigned)__popc(((unsigned)j ^ ml2) & zl) & 1u) << 31);
    }
    unsigned tid = blockIdx.x * 256u + (unsigned)t;   // [0, 65536)
    const float4* p0 = (const float4*)phi;
    const float4* p1 = (const float4*)(phi + DIMN);
    float t00 = 0.f, t11 = 0.f, t01 = 0.f, u01 = 0.f;
#pragma unroll
    for (int it = 0; it < 8; ++it) {
        unsigned gc = tid + (unsigned)it * 65536u;    // [0, 2^19)
        unsigned g = ((gc >> gb) << (gb + 1)) | (gc & ((1u << gb) - 1u));
        unsigned gx = g ^ mg4;
        float4 a0 = p0[g], a1 = p1[g];
        float4 b0 = p0[gx], b1 = p1[gx];
        if (ml2) {
            b0 = make_float4(b0.y, b0.x, b0.w, b0.z);
            b1 = make_float4(b1.y, b1.x, b1.w, b1.z);
        }
        unsigned fg = (((unsigned)__popc((g << 2) & zm) & 1u) << 31);
        unsigned fx = (((unsigned)__popc((gx << 2) & zm) & 1u) << 31);
        const float* A0 = &a0.x; const float* A1 = &a1.x;
        const float* B0 = &b0.x; const float* B1 = &b1.x;
#pragma unroll
        for (int j = 0; j < 4; ++j) {
            t00 += A0[j] * B0[j];
            t11 += A1[j] * B1[j];
            float p = A0[j] * B1[j], r = B0[j] * A1[j];
            t01 += p + r;
            u01 += fflip(p, fx ^ px31[j]) + fflip(r, fg ^ pg31[j]);
        }
    }
    t00 *= 2.f; t11 *= 2.f;
    int lane = t & 63, w = t >> 6;
    float vals[4] = { t00, t11, t01, u01 };
#pragma unroll
    for (int j = 0; j < 4; ++j) {
        float v = wave_sum(vals[j]);
        if (lane == 0) red[w * 4 + j] = v;
    }
    __syncthreads();
    if (t < 4) {
        float r = red[t] + red[4 + t] + red[8 + t] + red[12 + t];
        atomicAdd(&acc[4 * M.qn[slice] + t], r);
    }
}

// ---------------- finalize: combine 154 sums into the scalar loss ----------------
__global__ __launch_bounds__(64) void k_final(const float* __restrict__ acc,
                                              float* __restrict__ out) {
    int t = threadIdx.x;
    float v = 0.f;
    if (t < NQ) {
        float t00 = acc[4 * t], t11 = acc[4 * t + 1];
        float t01 = acc[4 * t + 2], u01 = acc[4 * t + 3];
        float d = t00 - t11;
        v = 0.5f * d * d + 2.f * t01 * t01 + 2.f * u01 * u01;   // X op + Y op
    } else if (t < 2 * NQ) {
        int q = t - NQ;
        float z0 = acc[4 * NQ + 3 * q], z1 = acc[4 * NQ + 3 * q + 1];
        float zz = acc[4 * NQ + 3 * q + 2];
        float d = z0 - z1;
        v = 0.5f * d * d + 2.f * zz * zz;                       // Z op
    }
    v += __shfl_down(v, 32); v += __shfl_down(v, 16); v += __shfl_down(v, 8);
    v += __shfl_down(v, 4);  v += __shfl_down(v, 2);  v += __shfl_down(v, 1);
    if (t == 0) out[0] = v;
}

extern "C" void kernel_launch(void* const* d_in, const int* in_sizes, int n_in,
                              void* d_out, int out_size, void* d_ws, size_t ws_size,
                              hipStream_t stream) {
    const float* theta = (const float*)d_in[0];
    float* out  = (float*)d_out;
    float* ws   = (float*)d_ws;
    float* phi  = ws;                          // 2 * DIMN floats (32 MB)
    float* acc  = ws + 2 * (size_t)DIMN;       // 256 floats
    float* trig = acc + 256;                   // 88 floats

    constexpr MaskSet M = buildMasks();

    Meas4Arg m4;
    const int qs[4] = { 0, 4, 9, 21 };
    for (int i = 0; i < 4; ++i) {
        int q = qs[i];
        m4.xm[i] = M.xm[q]; m4.zm[i] = M.zm[q];
        m4.gbit[i] = topbit_c(M.xm[q]) - 2;
        m4.qn[i] = q;
    }

    k_prep<<<1, 256, 0, stream>>>(theta, acc, trig);
    k_genHi<<<512, 256, 0, stream>>>(phi, trig, acc);
    k_midA<<<512, 256, 0, stream>>>(phi, trig, acc);
    k_low<<<1024, 512, 0, stream>>>(phi, trig, acc);
    k_measS<<<dim3(256, 4), 256, 0, stream>>>(phi, acc, m4);
    k_final<<<1, 64, 0, stream>>>(acc, out);
}